// Round 9
// baseline (79.861 us; speedup 1.0000x reference)
//
#include <hip/hip_runtime.h>

#define NQ 11
#define DIM 2048            // 1 << NQ
#define NL 5
#define NLAYERS 6           // NL variational + 1 final YZY
#define NGATES (NLAYERS * NQ)

struct c32 { float re, im; };

__device__ __forceinline__ c32 cmul(c32 a, c32 b) {
    return { a.re * b.re - a.im * b.im, a.re * b.im + a.im * b.re };
}
__device__ __forceinline__ c32 cmadd(c32 acc, c32 a, c32 b) {
    return { fmaf(a.re, b.re, fmaf(-a.im, b.im, acc.re)),
             fmaf(a.re, b.im, fmaf(a.im, b.re, acc.im)) };
}

// CNOT ring (q -> q+1 for q=0..9, then 10 -> 0) as one index permutation
// (scatter). Verified ≡ sequential cascade (R1 vs R5 bit-identical outputs).
__device__ __forceinline__ int ring_perm(int u) {
    int P = u ^ (u >> 1);
    P ^= P >> 2;
    P ^= P >> 4;
    P ^= P >> 8;
    return (P & 0x3FF) | (((P ^ (u >> 10)) & 1) << 10);
}

__global__ __launch_bounds__(1024) void qsim_kernel(
    const float* __restrict__ x,   // [B,1,NQ] f32
    const float* __restrict__ w,   // [198] f32
    float* __restrict__ out)       // f32: [B,32,32] REAL block, then IMAG block
{
    __shared__ c32 psi[DIM];
    __shared__ c32 gates[NGATES][4];

    const int b = blockIdx.x;
    const int t = threadIdx.x;

    // ---- fused YZY matrices (embedding folded into layer 0) ----
    if (t < NGATES) {
        const int l = t / NQ, q = t % NQ;
        const float* p = &w[l * 3 * NQ + q * 3];
        float c0, s0, cz, sz, c2, s2;
        sincosf(0.5f * p[0], &s0, &c0);
        sincosf(0.5f * p[1], &sz, &cz);
        sincosf(0.5f * p[2], &s2, &c2);
        c32 A00 = {  cz * c0, -sz * c0 };
        c32 A01 = { -cz * s0,  sz * s0 };
        c32 A10 = {  cz * s0,  sz * s0 };
        c32 A11 = {  cz * c0,  sz * c0 };
        c32 M00 = { c2 * A00.re - s2 * A10.re, c2 * A00.im - s2 * A10.im };
        c32 M01 = { c2 * A01.re - s2 * A11.re, c2 * A01.im - s2 * A11.im };
        c32 M10 = { s2 * A00.re + c2 * A10.re, s2 * A00.im + c2 * A10.im };
        c32 M11 = { s2 * A01.re + c2 * A11.re, s2 * A01.im + c2 * A11.im };
        if (l == 0) {
            float ce, se;
            sincosf(0.5f * x[b * NQ + q], &se, &ce);
            c32 N00 = { M00.re * ce + M01.re * se, M00.im * ce + M01.im * se };
            c32 N01 = { M01.re * ce - M00.re * se, M01.im * ce - M00.im * se };
            c32 N10 = { M10.re * ce + M11.re * se, M10.im * ce + M11.im * se };
            c32 N11 = { M11.re * ce - M10.re * se, M11.im * ce - M10.im * se };
            M00 = N00; M01 = N01; M10 = N10; M11 = N11;
        }
        gates[t][0] = M00; gates[t][1] = M01;
        gates[t][2] = M10; gates[t][3] = M11;
    }

    // ---- |0...0> ----
    psi[t]        = { (t == 0) ? 1.f : 0.f, 0.f };
    psi[t + 1024] = { 0.f, 0.f };
    __syncthreads();

    // ---- circuit ----
    for (int l = 0; l < NLAYERS; l++) {
        for (int q = 0; q < NQ; q++) {
            const int bp = 10 - q;
            const int lo = t & ((1 << bp) - 1);
            const int i0 = ((t >> bp) << (bp + 1)) | lo;
            const int i1 = i0 | (1 << bp);
            const c32 m00 = gates[l * NQ + q][0];
            const c32 m01 = gates[l * NQ + q][1];
            const c32 m10 = gates[l * NQ + q][2];
            const c32 m11 = gates[l * NQ + q][3];
            const c32 a0 = psi[i0];
            const c32 a1 = psi[i1];
            psi[i0] = cmadd(cmul(m00, a0), m01, a1);
            psi[i1] = cmadd(cmul(m10, a0), m11, a1);
            __syncthreads();
        }
        if (l < NL) {
            const c32 v0 = psi[t];
            const c32 v1 = psi[t + 1024];
            const int d0 = ring_perm(t);
            const int d1 = ring_perm(t + 1024);
            __syncthreads();
            psi[d0] = v0;
            psi[d1] = v1;
            __syncthreads();
        }
    }

    // ---- partial trace keeping the LAST 5 qubits (low bits) ----
    // rho[b][j][k] = sum_{i<64} psi[i*32+j] * conj(psi[i*32+k])
    const int j = t >> 5, k = t & 31;
    float re = 0.f, im = 0.f;
#pragma unroll 8
    for (int i = 0; i < 64; i++) {
        const c32 a = psi[i * 32 + j];
        const c32 c = psi[i * 32 + k];
        re = fmaf(a.re, c.re, fmaf(a.im, c.im, re));
        im = fmaf(a.im, c.re, fmaf(-a.re, c.im, im));
    }
    // PLANAR f32 layout: real block [0,16384), imag block [16384,32768).
    // (R1 proved writes through f32 index 32767 are within the allocation.)
    out[b * 1024 + t]         = re;
    out[16384 + b * 1024 + t] = im;
}

extern "C" void kernel_launch(void* const* d_in, const int* in_sizes, int n_in,
                              void* d_out, int out_size, void* d_ws, size_t ws_size,
                              hipStream_t stream) {
    const float* x = (const float*)d_in[0];   // [B,1,NQ] f32
    const float* w = (const float*)d_in[1];   // [198] f32
    float* out = (float*)d_out;
    qsim_kernel<<<16, 1024, 0, stream>>>(x, w, out);
}